// Round 4
// baseline (2544.420 us; speedup 1.0000x reference)
//
#include <hip/hip_runtime.h>
#include <hip/hip_bf16.h>

static constexpr int DIN = 128;
static constexpr int HID = 64;

// ===========================================================================
// sage_mm (all-fp32): out[n,j] = sum_k X[n,k]*W[k,j]
//                                (+ acc[n,j]/max(cnt[n],1) + b[j] if HAS_ACC)
//   Block = 256 threads, 64 nodes/block. X tile + W staged in LDS.
//   W kept in natural [k][64] layout: lane j reads sW[k*64+j] -> stride-1
//   across lanes (2-way bank aliasing, free). X rows read as broadcast float4.
//   In-place out==acc is safe: each (n,j) read+written by one thread.
// ===========================================================================
template<int K, bool HAS_ACC>
__global__ __launch_bounds__(256) void sage_mm(
    const float* __restrict__ x, const float* __restrict__ W,
    const float* __restrict__ bias,
    const float* __restrict__ acc, const float* __restrict__ cnt,
    float* __restrict__ out, int N)
{
    __shared__ float sX[64 * K];
    __shared__ float sW[K * 64];
    const int tid = threadIdx.x;
    const int base = blockIdx.x * 64;

    // stage W (linear copy, coalesced)
    for (int e = tid; e < K * 64; e += 256) sW[e] = W[e];

    // stage X tile [64 x K] with coalesced float4 loads
    {
        const int CPR = K / 4;                     // float4 chunks per row
        const float4* xp = (const float4*)x;
        for (int c = tid; c < 64 * CPR; c += 256) {
            int r = c / CPR, cc = c % CPR;
            int n = base + r;
            float4 u = make_float4(0.f, 0.f, 0.f, 0.f);
            if (n < N) u = xp[(long long)n * CPR + cc];
            float* dst = &sX[r * K + cc * 4];
            dst[0] = u.x; dst[1] = u.y; dst[2] = u.z; dst[3] = u.w;
        }
    }
    __syncthreads();

    const int j  = tid & 63;     // output column
    const int wv = tid >> 6;     // wave id: 16 nodes per wave
    const float bj = HAS_ACC ? bias[j] : 0.0f;

    for (int t0 = wv * 16; t0 < wv * 16 + 16; t0 += 4) {
        float a[4] = {0.f, 0.f, 0.f, 0.f};
        #pragma unroll 8
        for (int k = 0; k < K; k += 4) {
            float w0 = sW[(k + 0) * 64 + j];
            float w1 = sW[(k + 1) * 64 + j];
            float w2 = sW[(k + 2) * 64 + j];
            float w3 = sW[(k + 3) * 64 + j];
            #pragma unroll
            for (int i = 0; i < 4; ++i) {
                const float4 x4 = *(const float4*)&sX[(t0 + i) * K + k];
                a[i] = fmaf(x4.x, w0, fmaf(x4.y, w1,
                       fmaf(x4.z, w2, fmaf(x4.w, w3, a[i]))));
            }
        }
        #pragma unroll
        for (int i = 0; i < 4; ++i) {
            int n = base + t0 + i;
            if (n >= N) break;
            float v = a[i];
            if (HAS_ACC)
                v = acc[(long long)n * 64 + j] * (1.0f / fmaxf(cnt[n], 1.0f)) + v + bj;
            out[(long long)n * 64 + j] = v;
        }
    }
}

// ===========================================================================
// scatter: acc[dst[e], :] += rows[src[e], :]; one thread per (edge, 4 dims)
// ===========================================================================
__global__ __launch_bounds__(256) void scatter_kernel(
    const float* __restrict__ rows, const int* __restrict__ src,
    const int* __restrict__ dst, float* __restrict__ acc,
    float* __restrict__ cnt, int nE)
{
    long long idx = (long long)blockIdx.x * blockDim.x + threadIdx.x;
    if (idx >= (long long)nE * 16) return;
    int e = (int)(idx >> 4);
    int q = ((int)idx & 15) * 4;
    int s = src[e], d = dst[e];
    float4 v = *(const float4*)&rows[(long long)s * 64 + q];
    float* ap = acc + (long long)d * 64 + q;
    atomicAdd(ap + 0, v.x);
    atomicAdd(ap + 1, v.y);
    atomicAdd(ap + 2, v.z);
    atomicAdd(ap + 3, v.w);
    if (cnt != nullptr && q == 0) atomicAdd(cnt + d, 1.0f);
}

extern "C" void kernel_launch(void* const* d_in, const int* in_sizes, int n_in,
                              void* d_out, int out_size, void* d_ws, size_t ws_size,
                              hipStream_t stream) {
    const float* x_d    = (const float*)d_in[0];
    const float* x_g    = (const float*)d_in[1];
    const int* src_dg   = (const int*)d_in[2];
    const int* dst_dg   = (const int*)d_in[3];
    const int* src_gd   = (const int*)d_in[4];
    const int* dst_gd   = (const int*)d_in[5];
    const float* Wl1_dg = (const float*)d_in[6];
    const float* bl1_dg = (const float*)d_in[7];
    const float* Wr1_dg = (const float*)d_in[8];
    const float* Wl1_gd = (const float*)d_in[9];
    const float* bl1_gd = (const float*)d_in[10];
    const float* Wr1_gd = (const float*)d_in[11];
    const float* Wl2_dg = (const float*)d_in[12];
    const float* bl2_dg = (const float*)d_in[13];
    const float* Wr2_dg = (const float*)d_in[14];
    const float* Wl2_gd = (const float*)d_in[15];
    const float* bl2_gd = (const float*)d_in[16];
    const float* Wr2_gd = (const float*)d_in[17];

    const int nd = in_sizes[0] / DIN;   // 50000
    const int ng = in_sizes[1] / DIN;   // 100000
    const int ne = in_sizes[2];         // 600000

    // ---- workspace (fp32), proven round-1 layout (~77.4 MB) ----
    float* base = (float*)d_ws;
    float* cntG = base + 64;                       // [ng]
    float* cntD = cntG + (size_t)ng;               // [nd]
    float* g1   = cntD + (size_t)nd;               // [ng,64] acc -> layer1 out (in place)
    float* d1   = g1 + (size_t)ng * HID;           // [nd,64] acc -> layer1 out (in place)
    float* D2A  = d1 + (size_t)nd * HID;           // [nd,64]
    float* P    = D2A + (size_t)nd * HID;          // [ng,64] projection scratch
    float* G2A  = d1;                              // d1+D2A span reused (ng == 2*nd)

    float* out   = (float*)d_out;
    float* d2out = out;                            // [nd,64]
    float* g2out = out + (size_t)nd * HID;         // [ng,64]

    const int block = 256;
    const int gN_g  = (ng + 63) / 64;
    const int gN_d  = (nd + 63) / 64;
    const int gE    = (int)(((long long)ne * 16 + block - 1) / block);

    // zero cntG,cntD,g1,d1 (contiguous)
    hipMemsetAsync(cntG, 0, ((size_t)(ng + nd) + (size_t)(ng + nd) * HID) * sizeof(float), stream);

    // ---- layer 1, d->g : g1 ----
    sage_mm<DIN, false><<<gN_d, block, 0, stream>>>(x_d, Wl1_dg, nullptr, nullptr, nullptr, P, nd);
    scatter_kernel<<<gE, block, 0, stream>>>(P, src_dg, dst_dg, g1, cntG, ne);
    sage_mm<DIN, true><<<gN_g, block, 0, stream>>>(x_g, Wr1_dg, bl1_dg, g1, cntG, g1, ng);

    // ---- layer 1, g->d : d1 ----
    sage_mm<DIN, false><<<gN_g, block, 0, stream>>>(x_g, Wl1_gd, nullptr, nullptr, nullptr, P, ng);
    scatter_kernel<<<gE, block, 0, stream>>>(P, src_gd, dst_gd, d1, cntD, ne);
    sage_mm<DIN, true><<<gN_d, block, 0, stream>>>(x_d, Wr1_gd, bl1_gd, d1, cntD, d1, nd);

    // ---- layer 2, g->d : d2 -> d_out[0 : nd*64] ----
    sage_mm<HID, false><<<gN_g, block, 0, stream>>>(g1, Wl2_gd, nullptr, nullptr, nullptr, P, ng);
    hipMemsetAsync(D2A, 0, (size_t)nd * HID * sizeof(float), stream);
    scatter_kernel<<<gE, block, 0, stream>>>(P, src_gd, dst_gd, D2A, nullptr, ne);
    // project d1 before its region is recycled; P is dead after the scatter above
    sage_mm<HID, false><<<gN_d, block, 0, stream>>>(d1, Wl2_dg, nullptr, nullptr, nullptr, P, nd);
    sage_mm<HID, true><<<gN_d, block, 0, stream>>>(d1, Wr2_gd, bl2_gd, D2A, cntD, d2out, nd);

    // ---- layer 2, d->g : g2 -> d_out[nd*64 : ] ----
    // d1 and D2A are both dead now; their contiguous span becomes G2A [ng,64]
    hipMemsetAsync(G2A, 0, (size_t)ng * HID * sizeof(float), stream);
    scatter_kernel<<<gE, block, 0, stream>>>(P, src_dg, dst_dg, G2A, nullptr, ne);
    sage_mm<HID, true><<<gN_g, block, 0, stream>>>(g1, Wr2_dg, bl2_dg, G2A, cntG, g2out, ng);
}

// Round 5
// 1242.201 us; speedup vs baseline: 2.0483x; 2.0483x over previous
//
#include <hip/hip_runtime.h>
#include <hip/hip_bf16.h>

static constexpr int DIN = 128;
static constexpr int HID = 64;

// ===========================================================================
// CSR build: counting sort of edges by dst. Per graph:
//   hist -> exclusive scan (3-kernel) -> atomic-cursor placement.
// After placement, cur[n] == end offset of node n; start(n) = cur[n-1] (0 for n=0).
// ===========================================================================
__global__ __launch_bounds__(256) void hist_kernel(const int* __restrict__ dst,
                                                   int* __restrict__ cnt, int nE) {
    int i = blockIdx.x * blockDim.x + threadIdx.x;
    if (i < nE) atomicAdd(&cnt[dst[i]], 1);
}

// per-block exclusive scan of 1024-chunks; block totals -> bsum
__global__ __launch_bounds__(1024) void scan1_kernel(const int* __restrict__ cnt,
                                                     int* __restrict__ cur,
                                                     int* __restrict__ bsum, int N) {
    __shared__ int s[1024];
    int gid = blockIdx.x * 1024 + threadIdx.x;
    int v = (gid < N) ? cnt[gid] : 0;
    s[threadIdx.x] = v;
    __syncthreads();
    for (int o = 1; o < 1024; o <<= 1) {
        int t = (threadIdx.x >= o) ? s[threadIdx.x - o] : 0;
        __syncthreads();
        s[threadIdx.x] += t;
        __syncthreads();
    }
    if (gid < N) cur[gid] = s[threadIdx.x] - v;          // exclusive within chunk
    if (threadIdx.x == 1023) bsum[blockIdx.x] = s[1023]; // chunk total
}

// single-block exclusive scan of block sums (nb <= 1024)
__global__ __launch_bounds__(1024) void scan2_kernel(int* __restrict__ bsum, int nb) {
    __shared__ int s[1024];
    int v = (threadIdx.x < nb) ? bsum[threadIdx.x] : 0;
    s[threadIdx.x] = v;
    __syncthreads();
    for (int o = 1; o < 1024; o <<= 1) {
        int t = (threadIdx.x >= o) ? s[threadIdx.x - o] : 0;
        __syncthreads();
        s[threadIdx.x] += t;
        __syncthreads();
    }
    if (threadIdx.x < nb) bsum[threadIdx.x] = s[threadIdx.x] - v;  // exclusive
}

__global__ __launch_bounds__(1024) void scan3_kernel(int* __restrict__ cur,
                                                     const int* __restrict__ bsum, int N) {
    int gid = blockIdx.x * 1024 + threadIdx.x;
    if (gid < N) cur[gid] += bsum[blockIdx.x];
}

__global__ __launch_bounds__(256) void place_kernel(const int* __restrict__ src,
                                                    const int* __restrict__ dst,
                                                    int* __restrict__ cur,
                                                    int* __restrict__ col, int nE) {
    int i = blockIdx.x * blockDim.x + threadIdx.x;
    if (i < nE) {
        int p = atomicAdd(&cur[dst[i]], 1);
        col[p] = src[i];
    }
}

// ===========================================================================
// sage_mm (projection): out[n,j] = sum_k X[n,k]*W[k,j]. fp32. 64 nodes/block.
// ===========================================================================
template<int K>
__global__ __launch_bounds__(256) void sage_mm(
    const float* __restrict__ x, const float* __restrict__ W,
    float* __restrict__ out, int N)
{
    __shared__ float sX[64 * K];
    __shared__ float sW[K * 64];
    const int tid = threadIdx.x;
    const int base = blockIdx.x * 64;

    for (int e = tid; e < K * 64; e += 256) sW[e] = W[e];
    {
        const int CPR = K / 4;
        const float4* xp = (const float4*)x;
        for (int c = tid; c < 64 * CPR; c += 256) {
            int r = c / CPR, cc = c % CPR;
            int n = base + r;
            float4 u = make_float4(0.f, 0.f, 0.f, 0.f);
            if (n < N) u = xp[(long long)n * CPR + cc];
            float* dst = &sX[r * K + cc * 4];
            dst[0] = u.x; dst[1] = u.y; dst[2] = u.z; dst[3] = u.w;
        }
    }
    __syncthreads();

    const int j  = tid & 63;
    const int wv = tid >> 6;

    for (int t0 = wv * 16; t0 < wv * 16 + 16; t0 += 4) {
        float a[4] = {0.f, 0.f, 0.f, 0.f};
        #pragma unroll 8
        for (int k = 0; k < K; k += 4) {
            float w0 = sW[(k + 0) * 64 + j];
            float w1 = sW[(k + 1) * 64 + j];
            float w2 = sW[(k + 2) * 64 + j];
            float w3 = sW[(k + 3) * 64 + j];
            #pragma unroll
            for (int i = 0; i < 4; ++i) {
                const float4 x4 = *(const float4*)&sX[(t0 + i) * K + k];
                a[i] = fmaf(x4.x, w0, fmaf(x4.y, w1,
                       fmaf(x4.z, w2, fmaf(x4.w, w3, a[i]))));
            }
        }
        #pragma unroll
        for (int i = 0; i < 4; ++i) {
            int n = base + t0 + i;
            if (n >= N) break;
            out[(long long)n * 64 + j] = a[i];
        }
    }
}

// ===========================================================================
// sage_fused: out[n,j] = mean_{e in CSR(n)} P[col[e], j] + sum_k X2[n,k]*Wr[k,j] + b[j]
//   Gather runs 4 node-chains interleaved for ILP. Lanes j=0..63 read
//   consecutive 256B rows of P (coalesced, L2/L3-resident table).
// ===========================================================================
template<int K>
__global__ __launch_bounds__(256) void sage_fused(
    const float* __restrict__ P, const int* __restrict__ ends,
    const int* __restrict__ col,
    const float* __restrict__ x2, const float* __restrict__ Wr,
    const float* __restrict__ bias,
    float* __restrict__ out, int N)
{
    __shared__ float sX[64 * K];
    __shared__ float sW[K * 64];
    const int tid = threadIdx.x;
    const int base = blockIdx.x * 64;

    for (int e = tid; e < K * 64; e += 256) sW[e] = Wr[e];
    {
        const int CPR = K / 4;
        const float4* xp = (const float4*)x2;
        for (int c = tid; c < 64 * CPR; c += 256) {
            int r = c / CPR, cc = c % CPR;
            int n = base + r;
            float4 u = make_float4(0.f, 0.f, 0.f, 0.f);
            if (n < N) u = xp[(long long)n * CPR + cc];
            float* dst = &sX[r * K + cc * 4];
            dst[0] = u.x; dst[1] = u.y; dst[2] = u.z; dst[3] = u.w;
        }
    }
    __syncthreads();

    const int j  = tid & 63;
    const int wv = tid >> 6;
    const float bj = bias[j];

    for (int t0 = wv * 16; t0 < wv * 16 + 16; t0 += 4) {
        // dense part: 4-node register blocking
        float a[4] = {0.f, 0.f, 0.f, 0.f};
        #pragma unroll 8
        for (int k = 0; k < K; k += 4) {
            float w0 = sW[(k + 0) * 64 + j];
            float w1 = sW[(k + 1) * 64 + j];
            float w2 = sW[(k + 2) * 64 + j];
            float w3 = sW[(k + 3) * 64 + j];
            #pragma unroll
            for (int i = 0; i < 4; ++i) {
                const float4 x4 = *(const float4*)&sX[(t0 + i) * K + k];
                a[i] = fmaf(x4.x, w0, fmaf(x4.y, w1,
                       fmaf(x4.z, w2, fmaf(x4.w, w3, a[i]))));
            }
        }
        // gather part: 4 interleaved node chains
        int e0[4], e1[4];
        float m[4] = {0.f, 0.f, 0.f, 0.f};
        #pragma unroll
        for (int i = 0; i < 4; ++i) {
            int n = base + t0 + i;
            if (n < N) {
                e0[i] = (n == 0) ? 0 : ends[n - 1];
                e1[i] = ends[n];
            } else { e0[i] = 0; e1[i] = 0; }
        }
        bool any = true;
        while (any) {
            any = false;
            #pragma unroll
            for (int i = 0; i < 4; ++i) {
                if (e0[i] < e1[i]) {
                    int s = col[e0[i]];
                    m[i] += P[(long long)s * 64 + j];
                    e0[i]++;
                    any = true;
                }
            }
        }
        #pragma unroll
        for (int i = 0; i < 4; ++i) {
            int n = base + t0 + i;
            if (n >= N) break;
            int nn = base + t0 + i;
            int st = (nn == 0) ? 0 : ends[nn - 1];
            int deg = ends[nn] - st;
            float v = a[i] + bj;
            if (deg > 0) v += m[i] / (float)deg;
            out[(long long)n * 64 + j] = v;
        }
    }
}

extern "C" void kernel_launch(void* const* d_in, const int* in_sizes, int n_in,
                              void* d_out, int out_size, void* d_ws, size_t ws_size,
                              hipStream_t stream) {
    const float* x_d    = (const float*)d_in[0];
    const float* x_g    = (const float*)d_in[1];
    const int* src_dg   = (const int*)d_in[2];
    const int* dst_dg   = (const int*)d_in[3];
    const int* src_gd   = (const int*)d_in[4];
    const int* dst_gd   = (const int*)d_in[5];
    const float* Wl1_dg = (const float*)d_in[6];
    const float* bl1_dg = (const float*)d_in[7];
    const float* Wr1_dg = (const float*)d_in[8];
    const float* Wl1_gd = (const float*)d_in[9];
    const float* bl1_gd = (const float*)d_in[10];
    const float* Wr1_gd = (const float*)d_in[11];
    const float* Wl2_dg = (const float*)d_in[12];
    const float* bl2_dg = (const float*)d_in[13];
    const float* Wr2_dg = (const float*)d_in[14];
    const float* Wl2_gd = (const float*)d_in[15];
    const float* bl2_gd = (const float*)d_in[16];
    const float* Wr2_gd = (const float*)d_in[17];

    const int nd = in_sizes[0] / DIN;   // 50000
    const int ng = in_sizes[1] / DIN;   // 100000
    const int ne = in_sizes[2];         // 600000

    // ---- workspace layout: floats then ints, ~70 MB total ----
    float* g1 = (float*)d_ws;                      // [ng,64]
    float* d1 = g1 + (size_t)ng * HID;             // [nd,64]
    float* P  = d1 + (size_t)nd * HID;             // [ng,64] projection scratch
    int* ib   = (int*)(P + (size_t)ng * HID);
    int* curG = ib;                                // [ng]  CSR(dg) ends
    int* curD = curG + ng;                         // [nd]  CSR(gd) ends
    int* colG = curD + nd;                         // [ne]  src diseases, grouped by dst gene
    int* colD = colG + ne;                         // [ne]  src genes, grouped by dst disease
    int* cntG = colD + ne;                         // [ng]  scratch
    int* cntD = cntG + ng;                         // [nd]  scratch
    int* bsum = cntD + nd;                         // [1024]

    float* out   = (float*)d_out;
    float* d2out = out;                            // [nd,64]
    float* g2out = out + (size_t)nd * HID;         // [ng,64]

    const int gE256 = (ne + 255) / 256;
    const int nbG = (ng + 1023) / 1024;
    const int nbD = (nd + 1023) / 1024;
    const int gN_g = (ng + 63) / 64;
    const int gN_d = (nd + 63) / 64;

    // ---- build CSR for both graphs (edge lists shared by both layers) ----
    hipMemsetAsync(cntG, 0, (size_t)(ng + nd) * sizeof(int), stream);

    hist_kernel<<<gE256, 256, 0, stream>>>(dst_dg, cntG, ne);
    scan1_kernel<<<nbG, 1024, 0, stream>>>(cntG, curG, bsum, ng);
    scan2_kernel<<<1, 1024, 0, stream>>>(bsum, nbG);
    scan3_kernel<<<nbG, 1024, 0, stream>>>(curG, bsum, ng);
    place_kernel<<<gE256, 256, 0, stream>>>(src_dg, dst_dg, curG, colG, ne);

    hist_kernel<<<gE256, 256, 0, stream>>>(dst_gd, cntD, ne);
    scan1_kernel<<<nbD, 1024, 0, stream>>>(cntD, curD, bsum, nd);
    scan2_kernel<<<1, 1024, 0, stream>>>(bsum, nbD);
    scan3_kernel<<<nbD, 1024, 0, stream>>>(curD, bsum, nd);
    place_kernel<<<gE256, 256, 0, stream>>>(src_gd, dst_gd, curD, colD, ne);

    // ---- layer 1 ----
    sage_mm<DIN><<<gN_d, 256, 0, stream>>>(x_d, Wl1_dg, P, nd);
    sage_fused<DIN><<<gN_g, 256, 0, stream>>>(P, curG, colG, x_g, Wr1_dg, bl1_dg, g1, ng);

    sage_mm<DIN><<<gN_g, 256, 0, stream>>>(x_g, Wl1_gd, P, ng);
    sage_fused<DIN><<<gN_d, 256, 0, stream>>>(P, curD, colD, x_d, Wr1_gd, bl1_gd, d1, nd);

    // ---- layer 2 ----
    sage_mm<HID><<<gN_g, 256, 0, stream>>>(g1, Wl2_gd, P, ng);
    sage_fused<HID><<<gN_d, 256, 0, stream>>>(P, curD, colD, d1, Wr2_gd, bl2_gd, d2out, nd);

    sage_mm<HID><<<gN_d, 256, 0, stream>>>(d1, Wl2_dg, P, nd);
    sage_fused<HID><<<gN_g, 256, 0, stream>>>(P, curG, colG, g1, Wr2_dg, bl2_dg, g2out, ng);
}

// Round 6
// 704.520 us; speedup vs baseline: 3.6116x; 1.7632x over previous
//
#include <hip/hip_runtime.h>

static constexpr int DIN = 128;
static constexpr int HID = 64;

// ===========================================================================
// CSR build: counting sort of edges by dst (proven round-4 code).
// After placement, cur[n] == end offset of node n; start(n) = cur[n-1].
// ===========================================================================
__global__ __launch_bounds__(256) void hist_kernel(const int* __restrict__ dst,
                                                   int* __restrict__ cnt, int nE) {
    int i = blockIdx.x * blockDim.x + threadIdx.x;
    if (i < nE) atomicAdd(&cnt[dst[i]], 1);
}

__global__ __launch_bounds__(1024) void scan1_kernel(const int* __restrict__ cnt,
                                                     int* __restrict__ cur,
                                                     int* __restrict__ bsum, int N) {
    __shared__ int s[1024];
    int gid = blockIdx.x * 1024 + threadIdx.x;
    int v = (gid < N) ? cnt[gid] : 0;
    s[threadIdx.x] = v;
    __syncthreads();
    for (int o = 1; o < 1024; o <<= 1) {
        int t = (threadIdx.x >= o) ? s[threadIdx.x - o] : 0;
        __syncthreads();
        s[threadIdx.x] += t;
        __syncthreads();
    }
    if (gid < N) cur[gid] = s[threadIdx.x] - v;
    if (threadIdx.x == 1023) bsum[blockIdx.x] = s[1023];
}

__global__ __launch_bounds__(1024) void scan2_kernel(int* __restrict__ bsum, int nb) {
    __shared__ int s[1024];
    int v = (threadIdx.x < nb) ? bsum[threadIdx.x] : 0;
    s[threadIdx.x] = v;
    __syncthreads();
    for (int o = 1; o < 1024; o <<= 1) {
        int t = (threadIdx.x >= o) ? s[threadIdx.x - o] : 0;
        __syncthreads();
        s[threadIdx.x] += t;
        __syncthreads();
    }
    if (threadIdx.x < nb) bsum[threadIdx.x] = s[threadIdx.x] - v;
}

__global__ __launch_bounds__(1024) void scan3_kernel(int* __restrict__ cur,
                                                     const int* __restrict__ bsum, int N) {
    int gid = blockIdx.x * 1024 + threadIdx.x;
    if (gid < N) cur[gid] += bsum[blockIdx.x];
}

__global__ __launch_bounds__(256) void place_kernel(const int* __restrict__ src,
                                                    const int* __restrict__ dst,
                                                    int* __restrict__ cur,
                                                    int* __restrict__ col, int nE) {
    int i = blockIdx.x * blockDim.x + threadIdx.x;
    if (i < nE) {
        int p = atomicAdd(&cur[dst[i]], 1);
        col[p] = src[i];
    }
}

// ===========================================================================
// gather_mean: out[n, :] = mean_{e in CSR(n)} P[col[e], :]
//   No LDS, low VGPR -> high occupancy for latency hiding.
//   Wave = 4 node chains; lane group g=lane>>4 owns node wid*4+g.
//   Each lane reads float4 at columns (lane&15)*4 -> 16 lanes cover one
//   256B P-row; one load instruction fetches 4 rows (one per group).
//   Unroll-2 keeps 8 independent row loads in flight per wave.
// ===========================================================================
__global__ __launch_bounds__(256) void gather_mean(
    const float* __restrict__ P, const int* __restrict__ ends,
    const int* __restrict__ col, float* __restrict__ out, int N)
{
    const int lane = threadIdx.x & 63;
    const int wid  = (blockIdx.x * 256 + threadIdx.x) >> 6;
    const int n    = wid * 4 + (lane >> 4);
    const int c0   = (lane & 15) << 2;
    if (n >= N) return;

    int e        = (n == 0) ? 0 : ends[n - 1];
    const int e1 = ends[n];
    const int deg = e1 - e;

    float4 acc = make_float4(0.f, 0.f, 0.f, 0.f);
    while (e + 2 <= e1) {
        int s0 = col[e], s1 = col[e + 1];
        const float4 v0 = *(const float4*)&P[(long long)s0 * 64 + c0];
        const float4 v1 = *(const float4*)&P[(long long)s1 * 64 + c0];
        acc.x += v0.x + v1.x; acc.y += v0.y + v1.y;
        acc.z += v0.z + v1.z; acc.w += v0.w + v1.w;
        e += 2;
    }
    if (e < e1) {
        const float4 v0 = *(const float4*)&P[(long long)col[e] * 64 + c0];
        acc.x += v0.x; acc.y += v0.y; acc.z += v0.z; acc.w += v0.w;
    }
    const float inv = (deg > 0) ? 1.0f / (float)deg : 0.0f;
    acc.x *= inv; acc.y *= inv; acc.z *= inv; acc.w *= inv;
    *(float4*)&out[(long long)n * 64 + c0] = acc;
}

// ===========================================================================
// sage_mm<K,ADD>:
//   ADD=false: out[n,j]  = sum_k X[n,k]*W[k,j]                (projection)
//   ADD=true : out[n,j] += sum_k X[n,k]*W[k,j] + b[j]         (in-place comb
//              on top of the gather-written mean; one thread per (n,j))
//   Zero LDS bank conflicts (sW stride-1 across lanes; sX broadcast b128).
// ===========================================================================
template<int K, bool ADD>
__global__ __launch_bounds__(256) void sage_mm(
    const float* __restrict__ x, const float* __restrict__ W,
    const float* __restrict__ bias, float* __restrict__ out, int N)
{
    __shared__ float sX[64 * K];
    __shared__ float sW[K * 64];
    const int tid = threadIdx.x;
    const int base = blockIdx.x * 64;

    for (int e = tid; e < K * 64; e += 256) sW[e] = W[e];
    {
        const int CPR = K / 4;
        const float4* xp = (const float4*)x;
        for (int c = tid; c < 64 * CPR; c += 256) {
            int r = c / CPR, cc = c % CPR;
            int n = base + r;
            float4 u = make_float4(0.f, 0.f, 0.f, 0.f);
            if (n < N) u = xp[(long long)n * CPR + cc];
            float* dst = &sX[r * K + cc * 4];
            dst[0] = u.x; dst[1] = u.y; dst[2] = u.z; dst[3] = u.w;
        }
    }
    __syncthreads();

    const int j  = tid & 63;
    const int wv = tid >> 6;
    const float bj = ADD ? bias[j] : 0.0f;

    for (int t0 = wv * 16; t0 < wv * 16 + 16; t0 += 4) {
        float a[4] = {0.f, 0.f, 0.f, 0.f};
        #pragma unroll 8
        for (int k = 0; k < K; k += 4) {
            float w0 = sW[(k + 0) * 64 + j];
            float w1 = sW[(k + 1) * 64 + j];
            float w2 = sW[(k + 2) * 64 + j];
            float w3 = sW[(k + 3) * 64 + j];
            #pragma unroll
            for (int i = 0; i < 4; ++i) {
                const float4 x4 = *(const float4*)&sX[(t0 + i) * K + k];
                a[i] = fmaf(x4.x, w0, fmaf(x4.y, w1,
                       fmaf(x4.z, w2, fmaf(x4.w, w3, a[i]))));
            }
        }
        #pragma unroll
        for (int i = 0; i < 4; ++i) {
            int n = base + t0 + i;
            if (n >= N) break;
            long long o = (long long)n * 64 + j;
            float v = a[i];
            if (ADD) v += out[o] + bj;
            out[o] = v;
        }
    }
}

extern "C" void kernel_launch(void* const* d_in, const int* in_sizes, int n_in,
                              void* d_out, int out_size, void* d_ws, size_t ws_size,
                              hipStream_t stream) {
    const float* x_d    = (const float*)d_in[0];
    const float* x_g    = (const float*)d_in[1];
    const int* src_dg   = (const int*)d_in[2];
    const int* dst_dg   = (const int*)d_in[3];
    const int* src_gd   = (const int*)d_in[4];
    const int* dst_gd   = (const int*)d_in[5];
    const float* Wl1_dg = (const float*)d_in[6];
    const float* bl1_dg = (const float*)d_in[7];
    const float* Wr1_dg = (const float*)d_in[8];
    const float* Wl1_gd = (const float*)d_in[9];
    const float* bl1_gd = (const float*)d_in[10];
    const float* Wr1_gd = (const float*)d_in[11];
    const float* Wl2_dg = (const float*)d_in[12];
    const float* bl2_dg = (const float*)d_in[13];
    const float* Wr2_dg = (const float*)d_in[14];
    const float* Wl2_gd = (const float*)d_in[15];
    const float* bl2_gd = (const float*)d_in[16];
    const float* Wr2_gd = (const float*)d_in[17];

    const int nd = in_sizes[0] / DIN;   // 50000
    const int ng = in_sizes[1] / DIN;   // 100000
    const int ne = in_sizes[2];         // 600000

    // ---- workspace: floats then ints, ~70 MB (proven size) ----
    float* g1 = (float*)d_ws;                      // [ng,64]
    float* d1 = g1 + (size_t)ng * HID;             // [nd,64]
    float* P  = d1 + (size_t)nd * HID;             // [ng,64] projection scratch
    int* ib   = (int*)(P + (size_t)ng * HID);
    int* curG = ib;                                // [ng]  CSR(d->g) end offsets
    int* curD = curG + ng;                         // [nd]  CSR(g->d) end offsets
    int* colG = curD + nd;                         // [ne]
    int* colD = colG + ne;                         // [ne]
    int* cntG = colD + ne;                         // [ng]
    int* cntD = cntG + ng;                         // [nd]
    int* bsum = cntD + nd;                         // [1024]

    float* out   = (float*)d_out;
    float* d2out = out;                            // [nd,64]
    float* g2out = out + (size_t)nd * HID;         // [ng,64]

    const int gE256 = (ne + 255) / 256;
    const int nbG = (ng + 1023) / 1024;
    const int nbD = (nd + 1023) / 1024;
    const int gN_g = (ng + 63) / 64;
    const int gN_d = (nd + 63) / 64;
    const int gG_g = (ng + 15) / 16;               // gather grids: 16 nodes/block
    const int gG_d = (nd + 15) / 16;

    // ---- build CSR for both directions (edge lists shared by both layers) ----
    hipMemsetAsync(cntG, 0, (size_t)(ng + nd) * sizeof(int), stream);

    hist_kernel<<<gE256, 256, 0, stream>>>(dst_dg, cntG, ne);
    scan1_kernel<<<nbG, 1024, 0, stream>>>(cntG, curG, bsum, ng);
    scan2_kernel<<<1, 1024, 0, stream>>>(bsum, nbG);
    scan3_kernel<<<nbG, 1024, 0, stream>>>(curG, bsum, ng);
    place_kernel<<<gE256, 256, 0, stream>>>(src_dg, dst_dg, curG, colG, ne);

    hist_kernel<<<gE256, 256, 0, stream>>>(dst_gd, cntD, ne);
    scan1_kernel<<<nbD, 1024, 0, stream>>>(cntD, curD, bsum, nd);
    scan2_kernel<<<1, 1024, 0, stream>>>(bsum, nbD);
    scan3_kernel<<<nbD, 1024, 0, stream>>>(curD, bsum, nd);
    place_kernel<<<gE256, 256, 0, stream>>>(src_gd, dst_gd, curD, colD, ne);

    // ---- layer 1, d->g : g1 ----
    sage_mm<DIN, false><<<gN_d, 256, 0, stream>>>(x_d, Wl1_dg, nullptr, P, nd);
    gather_mean<<<gG_g, 256, 0, stream>>>(P, curG, colG, g1, ng);
    sage_mm<DIN, true><<<gN_g, 256, 0, stream>>>(x_g, Wr1_dg, bl1_dg, g1, ng);

    // ---- layer 1, g->d : d1 ----
    sage_mm<DIN, false><<<gN_g, 256, 0, stream>>>(x_g, Wl1_gd, nullptr, P, ng);
    gather_mean<<<gG_d, 256, 0, stream>>>(P, curD, colD, d1, nd);
    sage_mm<DIN, true><<<gN_d, 256, 0, stream>>>(x_d, Wr1_gd, bl1_gd, d1, nd);

    // ---- layer 2, g->d : d2 ----
    sage_mm<HID, false><<<gN_g, 256, 0, stream>>>(g1, Wl2_gd, nullptr, P, ng);
    gather_mean<<<gG_d, 256, 0, stream>>>(P, curD, colD, d2out, nd);
    sage_mm<HID, true><<<gN_d, 256, 0, stream>>>(d1, Wr2_gd, bl2_gd, d2out, nd);

    // ---- layer 2, d->g : g2 ----
    sage_mm<HID, false><<<gN_d, 256, 0, stream>>>(d1, Wl2_dg, nullptr, P, nd);
    gather_mean<<<gG_g, 256, 0, stream>>>(P, curG, colG, g2out, ng);
    sage_mm<HID, true><<<gN_g, 256, 0, stream>>>(g1, Wr2_dg, bl2_dg, g2out, ng);
}

// Round 7
// 554.215 us; speedup vs baseline: 4.5910x; 1.2712x over previous
//
#include <hip/hip_runtime.h>

static constexpr int DIN = 128;
static constexpr int HID = 64;

// ===========================================================================
// CSR build: counting sort of edges by dst (proven code).
// After placement, cur[n] == end offset of node n; start(n) = cur[n-1].
// ===========================================================================
__global__ __launch_bounds__(256) void hist_kernel(const int* __restrict__ dst,
                                                   int* __restrict__ cnt, int nE) {
    int i = blockIdx.x * blockDim.x + threadIdx.x;
    if (i < nE) atomicAdd(&cnt[dst[i]], 1);
}

__global__ __launch_bounds__(1024) void scan1_kernel(const int* __restrict__ cnt,
                                                     int* __restrict__ cur,
                                                     int* __restrict__ bsum, int N) {
    __shared__ int s[1024];
    int gid = blockIdx.x * 1024 + threadIdx.x;
    int v = (gid < N) ? cnt[gid] : 0;
    s[threadIdx.x] = v;
    __syncthreads();
    for (int o = 1; o < 1024; o <<= 1) {
        int t = (threadIdx.x >= o) ? s[threadIdx.x - o] : 0;
        __syncthreads();
        s[threadIdx.x] += t;
        __syncthreads();
    }
    if (gid < N) cur[gid] = s[threadIdx.x] - v;
    if (threadIdx.x == 1023) bsum[blockIdx.x] = s[1023];
}

__global__ __launch_bounds__(1024) void scan2_kernel(int* __restrict__ bsum, int nb) {
    __shared__ int s[1024];
    int v = (threadIdx.x < nb) ? bsum[threadIdx.x] : 0;
    s[threadIdx.x] = v;
    __syncthreads();
    for (int o = 1; o < 1024; o <<= 1) {
        int t = (threadIdx.x >= o) ? s[threadIdx.x - o] : 0;
        __syncthreads();
        s[threadIdx.x] += t;
        __syncthreads();
    }
    if (threadIdx.x < nb) bsum[threadIdx.x] = s[threadIdx.x] - v;
}

__global__ __launch_bounds__(1024) void scan3_kernel(int* __restrict__ cur,
                                                     const int* __restrict__ bsum, int N) {
    int gid = blockIdx.x * 1024 + threadIdx.x;
    if (gid < N) cur[gid] += bsum[blockIdx.x];
}

__global__ __launch_bounds__(256) void place_kernel(const int* __restrict__ src,
                                                    const int* __restrict__ dst,
                                                    int* __restrict__ cur,
                                                    int* __restrict__ col, int nE) {
    int i = blockIdx.x * blockDim.x + threadIdx.x;
    if (i < nE) {
        int p = atomicAdd(&cur[dst[i]], 1);
        col[p] = src[i];
    }
}

// ===========================================================================
// proj_dual<K>: Pa[n,j] = sum_k x[n,k]*Wa[k,j]; Pb[n,j] = sum_k x[n,k]*Wb[k,j]
//   64 nodes/block, 256 threads; K processed in 32-wide chunks so LDS is
//   only 24 KB (sX 8K + sW 16K) -> 4 blocks/CU (launch_bounds caps VGPR@128).
//   Wave wv owns nodes base+wv*16..+15; lane j = column; acc[16][2] in regs.
//   Pb == x (in-place) is safe: each block reads only its own 64 rows into
//   LDS before any write, and writes only those rows in the epilogue.
// ===========================================================================
template<int K>
__global__ __launch_bounds__(256, 4) void proj_dual(
    const float* __restrict__ x, const float* __restrict__ Wa,
    const float* __restrict__ Wb, float* __restrict__ Pa,
    float* __restrict__ Pb, int N)
{
    constexpr int KC = 32;
    __shared__ float sX[64 * KC];      // 8 KB
    __shared__ float sW[KC * 128];     // 16 KB: [kk][0:64]=Wa, [64:128]=Wb
    const int tid  = threadIdx.x;
    const int base = blockIdx.x * 64;
    const int j    = tid & 63;
    const int wv   = tid >> 6;

    float acc[16][2];
    #pragma unroll
    for (int i = 0; i < 16; ++i) { acc[i][0] = 0.f; acc[i][1] = 0.f; }

    for (int k0 = 0; k0 < K; k0 += KC) {
        // stage W chunk (coalesced: c is the fast index)
        for (int e = tid; e < KC * 64; e += 256) {
            int kk = e >> 6, c = e & 63;
            sW[kk * 128 + c]      = Wa[(k0 + kk) * 64 + c];
            sW[kk * 128 + 64 + c] = Wb[(k0 + kk) * 64 + c];
        }
        // stage X chunk [64][KC] via float4
        {
            constexpr int CPR = KC / 4;          // 8 chunks per row
            for (int c = tid; c < 64 * CPR; c += 256) {
                int r = c / CPR, cc = c % CPR;
                int n = base + r;
                float4 u = make_float4(0.f, 0.f, 0.f, 0.f);
                if (n < N) u = *(const float4*)&x[(long long)n * K + k0 + cc * 4];
                float* dp = &sX[r * KC + cc * 4];
                dp[0] = u.x; dp[1] = u.y; dp[2] = u.z; dp[3] = u.w;
            }
        }
        __syncthreads();

        #pragma unroll
        for (int kk = 0; kk < KC; kk += 4) {
            float wa[4], wb[4];
            #pragma unroll
            for (int q = 0; q < 4; ++q) {
                wa[q] = sW[(kk + q) * 128 + j];
                wb[q] = sW[(kk + q) * 128 + 64 + j];
            }
            #pragma unroll
            for (int i = 0; i < 16; ++i) {
                const float4 x4 = *(const float4*)&sX[(wv * 16 + i) * KC + kk];
                acc[i][0] = fmaf(x4.x, wa[0], fmaf(x4.y, wa[1],
                            fmaf(x4.z, wa[2], fmaf(x4.w, wa[3], acc[i][0]))));
                acc[i][1] = fmaf(x4.x, wb[0], fmaf(x4.y, wb[1],
                            fmaf(x4.z, wb[2], fmaf(x4.w, wb[3], acc[i][1]))));
            }
        }
        __syncthreads();
    }

    #pragma unroll
    for (int i = 0; i < 16; ++i) {
        int n = base + wv * 16 + i;
        if (n < N) {
            Pa[(long long)n * 64 + j] = acc[i][0];
            Pb[(long long)n * 64 + j] = acc[i][1];
        }
    }
}

// ===========================================================================
// gather_comb: out[n,:] += mean_{e in CSR(n)} P[col[e],:] + bias[:]
//   out already holds the self-term (x_dst @ Wr) written by proj_dual.
//   No LDS, low VGPR -> high occupancy. Wave = 4 node chains; lane group
//   (lane>>4) owns one node; 16 lanes x float4 cover the 256B P-row.
// ===========================================================================
__global__ __launch_bounds__(256) void gather_comb(
    const float* __restrict__ P, const int* __restrict__ ends,
    const int* __restrict__ col, const float* __restrict__ bias,
    float* __restrict__ out, int N)
{
    const int lane = threadIdx.x & 63;
    const int wid  = (blockIdx.x * 256 + threadIdx.x) >> 6;
    const int n    = wid * 4 + (lane >> 4);
    const int c0   = (lane & 15) << 2;
    if (n >= N) return;

    int e        = (n == 0) ? 0 : ends[n - 1];
    const int e1 = ends[n];
    const int deg = e1 - e;

    float4 acc = make_float4(0.f, 0.f, 0.f, 0.f);
    while (e + 2 <= e1) {
        int s0 = col[e], s1 = col[e + 1];
        const float4 v0 = *(const float4*)&P[(long long)s0 * 64 + c0];
        const float4 v1 = *(const float4*)&P[(long long)s1 * 64 + c0];
        acc.x += v0.x + v1.x; acc.y += v0.y + v1.y;
        acc.z += v0.z + v1.z; acc.w += v0.w + v1.w;
        e += 2;
    }
    if (e < e1) {
        const float4 v0 = *(const float4*)&P[(long long)col[e] * 64 + c0];
        acc.x += v0.x; acc.y += v0.y; acc.z += v0.z; acc.w += v0.w;
    }
    const float inv = (deg > 0) ? 1.0f / (float)deg : 0.0f;
    const float4 b4 = *(const float4*)&bias[c0];
    float4 cur = *(float4*)&out[(long long)n * 64 + c0];
    cur.x += acc.x * inv + b4.x;
    cur.y += acc.y * inv + b4.y;
    cur.z += acc.z * inv + b4.z;
    cur.w += acc.w * inv + b4.w;
    *(float4*)&out[(long long)n * 64 + c0] = cur;
}

extern "C" void kernel_launch(void* const* d_in, const int* in_sizes, int n_in,
                              void* d_out, int out_size, void* d_ws, size_t ws_size,
                              hipStream_t stream) {
    const float* x_d    = (const float*)d_in[0];
    const float* x_g    = (const float*)d_in[1];
    const int* src_dg   = (const int*)d_in[2];
    const int* dst_dg   = (const int*)d_in[3];
    const int* src_gd   = (const int*)d_in[4];
    const int* dst_gd   = (const int*)d_in[5];
    const float* Wl1_dg = (const float*)d_in[6];
    const float* bl1_dg = (const float*)d_in[7];
    const float* Wr1_dg = (const float*)d_in[8];
    const float* Wl1_gd = (const float*)d_in[9];
    const float* bl1_gd = (const float*)d_in[10];
    const float* Wr1_gd = (const float*)d_in[11];
    const float* Wl2_dg = (const float*)d_in[12];
    const float* bl2_dg = (const float*)d_in[13];
    const float* Wr2_dg = (const float*)d_in[14];
    const float* Wl2_gd = (const float*)d_in[15];
    const float* bl2_gd = (const float*)d_in[16];
    const float* Wr2_gd = (const float*)d_in[17];

    const int nd = in_sizes[0] / DIN;   // 50000
    const int ng = in_sizes[1] / DIN;   // 100000
    const int ne = in_sizes[2];         // 600000

    // ---- workspace: ~44 MB (well under proven 77 MB) ----
    float* P_d  = (float*)d_ws;                    // [nd,64] msg-projections
    float* P_g  = P_d + (size_t)nd * HID;          // [ng,64]
    int* endsG  = (int*)(P_g + (size_t)ng * HID);  // [ng] CSR(d->g) ends
    int* endsD  = endsG + ng;                      // [nd] CSR(g->d) ends
    int* colG   = endsD + nd;                      // [ne]
    int* colD   = colG + ne;                       // [ne]
    int* cntG   = colD + ne;                       // [ng] scratch
    int* cntD   = cntG + ng;                       // [nd] scratch
    int* bsum   = cntD + nd;                       // [1024]

    // d1/g1 live in the final output regions; proj2 overwrites them in place.
    float* out  = (float*)d_out;
    float* d1r  = out;                             // [nd,64] -> becomes d2
    float* g1r  = out + (size_t)nd * HID;          // [ng,64] -> becomes g2

    const int gE256 = (ne + 255) / 256;
    const int nbG   = (ng + 1023) / 1024;
    const int nbD   = (nd + 1023) / 1024;
    const int gN_g  = (ng + 63) / 64;
    const int gN_d  = (nd + 63) / 64;
    const int gG_g  = (ng + 15) / 16;
    const int gG_d  = (nd + 15) / 16;

    // ---- CSR build, both directions (edge lists shared by both layers) ----
    hipMemsetAsync(cntG, 0, (size_t)(ng + nd) * sizeof(int), stream);

    hist_kernel<<<gE256, 256, 0, stream>>>(dst_dg, cntG, ne);
    scan1_kernel<<<nbG, 1024, 0, stream>>>(cntG, endsG, bsum, ng);
    scan2_kernel<<<1, 1024, 0, stream>>>(bsum, nbG);
    scan3_kernel<<<nbG, 1024, 0, stream>>>(endsG, bsum, ng);
    place_kernel<<<gE256, 256, 0, stream>>>(src_dg, dst_dg, endsG, colG, ne);

    hist_kernel<<<gE256, 256, 0, stream>>>(dst_gd, cntD, ne);
    scan1_kernel<<<nbD, 1024, 0, stream>>>(cntD, endsD, bsum, nd);
    scan2_kernel<<<1, 1024, 0, stream>>>(bsum, nbD);
    scan3_kernel<<<nbD, 1024, 0, stream>>>(endsD, bsum, nd);
    place_kernel<<<gE256, 256, 0, stream>>>(src_gd, dst_gd, endsD, colD, ne);

    // ---- layer 1: dual projections (x read once each) ----
    // x_d -> msg-proj for genes (Wl1_dg) + self-term of d1 (Wr1_gd)
    proj_dual<DIN><<<gN_d, 256, 0, stream>>>(x_d, Wl1_dg, Wr1_gd, P_d, d1r, nd);
    // x_g -> msg-proj for diseases (Wl1_gd) + self-term of g1 (Wr1_dg)
    proj_dual<DIN><<<gN_g, 256, 0, stream>>>(x_g, Wl1_gd, Wr1_dg, P_g, g1r, ng);

    gather_comb<<<gG_g, 256, 0, stream>>>(P_d, endsG, colG, bl1_dg, g1r, ng);  // g1
    gather_comb<<<gG_d, 256, 0, stream>>>(P_g, endsD, colD, bl1_gd, d1r, nd);  // d1

    // ---- layer 2: dual projections, self-term written in place ----
    // g1 -> msg-proj for d2 (Wl2_gd) + self-term of g2 (Wr2_dg, in place)
    proj_dual<HID><<<gN_g, 256, 0, stream>>>(g1r, Wl2_gd, Wr2_dg, P_g, g1r, ng);
    // d1 -> msg-proj for g2 (Wl2_dg) + self-term of d2 (Wr2_gd, in place)
    proj_dual<HID><<<gN_d, 256, 0, stream>>>(d1r, Wl2_dg, Wr2_gd, P_d, d1r, nd);

    gather_comb<<<gG_d, 256, 0, stream>>>(P_g, endsD, colD, bl2_gd, d1r, nd);  // d2
    gather_comb<<<gG_g, 256, 0, stream>>>(P_d, endsG, colG, bl2_dg, g1r, ng);  // g2
}